// Round 4
// baseline (64.401 us; speedup 1.0000x reference)
//
#include <hip/hip_runtime.h>
#include <hip/hip_fp16.h>

// Problem constants (fixed by the reference)
#define S_N 32
#define O_N 64
#define A_N 8
#define R_N 8
#define B_N 1024
#define T_N 128

// Workspace layout:
//  u32 [0, 4096)      TH : packed fp16 transitions
//                     th[a][sl][k] = half2(Tr[2k][a][sl], Tr[2k+1][a][sl])
//                     at u32 index a*512 + sl*16 + k
//  f32 [4096, 6144)   OT[o][s]   = P(o|s)
//  f32 [6144, 8192)   RA[r*8+a][s] = P(r|s)*P(a|s)
//  f32 [8192, 8448)   RT[r][s]   = P(r|s)
//  f32 [8448, 8480)   PI[s]
#define OT_OFF   4096
#define RA_OFF   6144
#define RT_OFF   8192
#define PI_OFF   8448

// LDS emission block (floats): OT @0 (2048) | RA @2048 (2048) | RT @4096 (256) | PI @4352 (32)
#define L_OT 0
#define L_RA 2048
#define L_RT 4096
#define L_PI 4352
#define L_N  4384

__global__ __launch_bounds__(256) void tam_prep(
    const float* __restrict__ params_s,
    const float* __restrict__ params_s_sa,
    const float* __restrict__ params_o_s,
    const float* __restrict__ params_r_s,
    const float* __restrict__ params_a_s,
    float* __restrict__ ws)
{
    const int tid = threadIdx.x;
    if (blockIdx.x == 0) {
        // Transitions: 128 threads, each handles the (2*s2, 2*s2+1) row pair of
        // one action; packs the two softmaxed rows into half2 columns.
        if (tid < 128) {
            const int a = tid >> 4, s2 = tid & 15;
            const float* row0 = params_s_sa + ((2 * s2)     * A_N + a) * S_N;
            const float* row1 = params_s_sa + ((2 * s2 + 1) * A_N + a) * S_N;
            float p0[32], p1[32];
            #pragma unroll
            for (int i = 0; i < 8; ++i) {
                float4 v0 = reinterpret_cast<const float4*>(row0)[i];
                float4 v1 = reinterpret_cast<const float4*>(row1)[i];
                p0[4*i]=v0.x; p0[4*i+1]=v0.y; p0[4*i+2]=v0.z; p0[4*i+3]=v0.w;
                p1[4*i]=v1.x; p1[4*i+1]=v1.y; p1[4*i+2]=v1.z; p1[4*i+3]=v1.w;
            }
            float m0 = p0[0], m1 = p1[0];
            #pragma unroll
            for (int i = 1; i < 32; ++i) { m0 = fmaxf(m0, p0[i]); m1 = fmaxf(m1, p1[i]); }
            float s0 = 0.f, s1 = 0.f;
            #pragma unroll
            for (int i = 0; i < 32; ++i) {
                p0[i] = __expf(p0[i] - m0); s0 += p0[i];
                p1[i] = __expf(p1[i] - m1); s1 += p1[i];
            }
            const float i0 = 1.0f / s0, i1 = 1.0f / s1;
            __half2* wsh2 = reinterpret_cast<__half2*>(ws);
            #pragma unroll
            for (int sp = 0; sp < 32; ++sp)
                wsh2[a * 512 + sp * 16 + s2] = __floats2half2_rn(p0[sp] * i0, p1[sp] * i1);
        }
    } else {
        __shared__ float sRT[256], sAT[256];
        if (tid < 32) {
            // observation emission: softmax over O (64) per state; OT[o][s]
            const int s = tid;
            const float* row = params_o_s + s * O_N;
            float p[64];
            #pragma unroll
            for (int i = 0; i < 16; ++i) {
                float4 v = reinterpret_cast<const float4*>(row)[i];
                p[4*i]=v.x; p[4*i+1]=v.y; p[4*i+2]=v.z; p[4*i+3]=v.w;
            }
            float mx = p[0];
            #pragma unroll
            for (int i = 1; i < 64; ++i) mx = fmaxf(mx, p[i]);
            float sum = 0.f;
            #pragma unroll
            for (int i = 0; i < 64; ++i) { p[i] = __expf(p[i] - mx); sum += p[i]; }
            const float inv = 1.0f / sum;
            #pragma unroll
            for (int o = 0; o < 64; ++o) ws[OT_OFF + o * 32 + s] = p[o] * inv;
        } else if (tid < 64) {
            // reward emission: RT[r][s]
            const int s = tid - 32;
            const float* row = params_r_s + s * R_N;
            float p[8];
            #pragma unroll
            for (int i = 0; i < 2; ++i) {
                float4 v = reinterpret_cast<const float4*>(row)[i];
                p[4*i]=v.x; p[4*i+1]=v.y; p[4*i+2]=v.z; p[4*i+3]=v.w;
            }
            float mx = p[0];
            #pragma unroll
            for (int i = 1; i < 8; ++i) mx = fmaxf(mx, p[i]);
            float sum = 0.f;
            #pragma unroll
            for (int i = 0; i < 8; ++i) { p[i] = __expf(p[i] - mx); sum += p[i]; }
            const float inv = 1.0f / sum;
            #pragma unroll
            for (int r = 0; r < 8; ++r) {
                const float v = p[r] * inv;
                ws[RT_OFF + r * 32 + s] = v;
                sRT[r * 32 + s] = v;
            }
        } else if (tid < 96) {
            // action prior: AT[a][s] (LDS only, feeds RA)
            const int s = tid - 64;
            const float* row = params_a_s + s * A_N;
            float p[8];
            #pragma unroll
            for (int i = 0; i < 2; ++i) {
                float4 v = reinterpret_cast<const float4*>(row)[i];
                p[4*i]=v.x; p[4*i+1]=v.y; p[4*i+2]=v.z; p[4*i+3]=v.w;
            }
            float mx = p[0];
            #pragma unroll
            for (int i = 1; i < 8; ++i) mx = fmaxf(mx, p[i]);
            float sum = 0.f;
            #pragma unroll
            for (int i = 0; i < 8; ++i) { p[i] = __expf(p[i] - mx); sum += p[i]; }
            const float inv = 1.0f / sum;
            #pragma unroll
            for (int a = 0; a < 8; ++a) sAT[a * 32 + s] = p[a] * inv;
        } else if (tid < 128) {
            // pi = softmax(params_s): each thread computes redundantly, writes own elem
            const int s = tid - 96;
            float p[32];
            #pragma unroll
            for (int i = 0; i < 8; ++i) {
                float4 v = reinterpret_cast<const float4*>(params_s)[i];
                p[4*i]=v.x; p[4*i+1]=v.y; p[4*i+2]=v.z; p[4*i+3]=v.w;
            }
            float mx = p[0];
            #pragma unroll
            for (int i = 1; i < 32; ++i) mx = fmaxf(mx, p[i]);
            float sum = 0.f;
            #pragma unroll
            for (int i = 0; i < 32; ++i) { p[i] = __expf(p[i] - mx); sum += p[i]; }
            ws[PI_OFF + s] = p[s] / sum;
        }
        __syncthreads();
        // RA[r*8+a][s] = RT[r][s] * AT[a][s]
        #pragma unroll 1
        for (int i = tid; i < 2048; i += 256) {
            const int sl = i & 31, ra = i >> 5;
            ws[RA_OFF + i] = sRT[(ra >> 3) * 32 + sl] * sAT[(ra & 7) * 32 + sl];
        }
    }
}

#define RLI(v, l) __builtin_amdgcn_readlane((v), (l))
#define RLF(v, l) __int_as_float(__builtin_amdgcn_readlane(__float_as_int(v), (l)))

static __device__ __forceinline__ __half2 u2h(unsigned u) {
    union { unsigned u; __half2 h; } c; c.u = u; return c.h;
}

// Load all 16 packed half2 column entries of action A_'s transition matrix
#define LOADTH(TH, A_) {                                                     \
    const uint4* p_ = reinterpret_cast<const uint4*>(wsu + (A_) * 512 + sl * 16); \
    uint4 q0_ = p_[0], q1_ = p_[1], q2_ = p_[2], q3_ = p_[3];                \
    TH[0]=u2h(q0_.x); TH[1]=u2h(q0_.y); TH[2]=u2h(q0_.z); TH[3]=u2h(q0_.w);  \
    TH[4]=u2h(q1_.x); TH[5]=u2h(q1_.y); TH[6]=u2h(q1_.z); TH[7]=u2h(q1_.w);  \
    TH[8]=u2h(q2_.x); TH[9]=u2h(q2_.y); TH[10]=u2h(q2_.z); TH[11]=u2h(q2_.w);\
    TH[12]=u2h(q3_.x); TH[13]=u2h(q3_.y); TH[14]=u2h(q3_.z); TH[15]=u2h(q3_.w); }

// Emission factors for the step encoded in the low 16 bits of PKW (from LDS)
#define LOADE(EO, ERA, PKW) {                                                \
    const unsigned pk_ = (PKW);                                              \
    EO  = sE[(int)(pk_ & 63u) * 32 + sl];                                    \
    ERA = sE[eBase + (int)((pk_ >> 6) & 7u) * eMulR                          \
                   + (int)((pk_ >> 9) & 7u) * eMulA + sl]; }

// 16 half2-packed fma pairs against register-resident T (4 accumulator chains)
#define FMA16(TH)                                                            \
    c0=fmaf(w0, __low2float(TH[0]), c0); c1=fmaf(w1, __high2float(TH[0]), c1); \
    c2=fmaf(w2, __low2float(TH[1]), c2); c3=fmaf(w3, __high2float(TH[1]), c3); \
    c0=fmaf(w4, __low2float(TH[2]), c0); c1=fmaf(w5, __high2float(TH[2]), c1); \
    c2=fmaf(w6, __low2float(TH[3]), c2); c3=fmaf(w7, __high2float(TH[3]), c3); \
    c0=fmaf(w8, __low2float(TH[4]), c0); c1=fmaf(w9, __high2float(TH[4]), c1); \
    c2=fmaf(w10,__low2float(TH[5]), c2); c3=fmaf(w11,__high2float(TH[5]), c3); \
    c0=fmaf(w12,__low2float(TH[6]), c0); c1=fmaf(w13,__high2float(TH[6]), c1); \
    c2=fmaf(w14,__low2float(TH[7]), c2); c3=fmaf(w15,__high2float(TH[7]), c3); \
    c0=fmaf(w16,__low2float(TH[8]), c0); c1=fmaf(w17,__high2float(TH[8]), c1); \
    c2=fmaf(w18,__low2float(TH[9]), c2); c3=fmaf(w19,__high2float(TH[9]), c3); \
    c0=fmaf(w20,__low2float(TH[10]),c0); c1=fmaf(w21,__high2float(TH[10]),c1); \
    c2=fmaf(w22,__low2float(TH[11]),c2); c3=fmaf(w23,__high2float(TH[11]),c3); \
    c0=fmaf(w24,__low2float(TH[12]),c0); c1=fmaf(w25,__high2float(TH[12]),c1); \
    c2=fmaf(w26,__low2float(TH[13]),c2); c3=fmaf(w27,__high2float(TH[13]),c3); \
    c0=fmaf(w28,__low2float(TH[14]),c0); c1=fmaf(w29,__high2float(TH[14]),c1); \
    c2=fmaf(w30,__low2float(TH[15]),c2); c3=fmaf(w31,__high2float(TH[15]),c3);

// One HMM step: w = u .* e ; u' = T_a^T w. T selected by wave-uniform switch;
// all T register indices are compile-time constants.
#define STEP(EO, ERA, AV) {                                                  \
    const float wv = u * (EO) * (ERA);                                       \
    const float w0 =RLF(wv,0),  w1 =RLF(wv,1),  w2 =RLF(wv,2),  w3 =RLF(wv,3),  \
                w4 =RLF(wv,4),  w5 =RLF(wv,5),  w6 =RLF(wv,6),  w7 =RLF(wv,7),  \
                w8 =RLF(wv,8),  w9 =RLF(wv,9),  w10=RLF(wv,10), w11=RLF(wv,11), \
                w12=RLF(wv,12), w13=RLF(wv,13), w14=RLF(wv,14), w15=RLF(wv,15), \
                w16=RLF(wv,16), w17=RLF(wv,17), w18=RLF(wv,18), w19=RLF(wv,19), \
                w20=RLF(wv,20), w21=RLF(wv,21), w22=RLF(wv,22), w23=RLF(wv,23), \
                w24=RLF(wv,24), w25=RLF(wv,25), w26=RLF(wv,26), w27=RLF(wv,27), \
                w28=RLF(wv,28), w29=RLF(wv,29), w30=RLF(wv,30), w31=RLF(wv,31); \
    float c0 = 0.f, c1 = 0.f, c2 = 0.f, c3 = 0.f;                            \
    switch (AV) {                                                            \
        case 0: FMA16(th0); break; case 1: FMA16(th1); break;                \
        case 2: FMA16(th2); break; case 3: FMA16(th3); break;                \
        case 4: FMA16(th4); break; case 5: FMA16(th5); break;                \
        case 6: FMA16(th6); break; default: FMA16(th7); break;               \
    }                                                                        \
    u = (c0 + c1) + (c2 + c3); }

// One wave (64 lanes) per episode. lane&31 = destination state s' (halves
// replicated). All 8 T matrices live in VGPRs as packed fp16 (128 regs);
// emissions live in LDS, prefetched one step ahead.
__global__ __launch_bounds__(64, 1) void tam_main(
    const float* __restrict__ regime,
    const int*   __restrict__ obs,
    const int*   __restrict__ rewards,
    const int*   __restrict__ dones_i,   // float32 0/1 read as int bits
    const int*   __restrict__ actions,
    const float* __restrict__ ws,
    float* __restrict__ out)
{
    __shared__ float sE[L_N];            // 17.1 KB emission block
    const int lane = threadIdx.x;
    const int sl   = lane & 31;
    const int b    = blockIdx.x;
    const unsigned* wsu = reinterpret_cast<const unsigned*>(ws);

    // stage emission tables into LDS (single wave)
    {
        const float4* g4 = reinterpret_cast<const float4*>(ws + OT_OFF);
        float4* s4 = reinterpret_cast<float4*>(sE);
        #pragma unroll 1
        for (int i = lane; i < L_N / 4; i += 64) s4[i] = g4[i];
    }
    __syncthreads();

    // all 8 transition matrices into registers (packed fp16, 128 VGPRs)
    __half2 th0[16], th1[16], th2[16], th3[16], th4[16], th5[16], th6[16], th7[16];
    LOADTH(th0, 0) LOADTH(th1, 1) LOADTH(th2, 2) LOADTH(th3, 3)
    LOADTH(th4, 4) LOADTH(th5, 5) LOADTH(th6, 6) LOADTH(th7, 7)

    // per-lane packed step-pair indices: lane i holds steps 2i (low16), 2i+1 (high16)
    const int t0 = 2 * lane, t1 = 2 * lane + 1;
    const int o0 = obs[t0 * B_N + b],      o1 = obs[t1 * B_N + b];
    const int r0 = rewards[t0 * B_N + b],  r1 = rewards[t1 * B_N + b];
    const int a0 = actions[t0 * B_N + b],  a1 = actions[t1 * B_N + b];
    const int d0 = dones_i[t0 * B_N + b],  d1 = dones_i[t1 * B_N + b];
    const int vpk = (o0 | (r0 << 6) | (a0 << 9)) |
                    ((o1 | (r1 << 6) | (a1 << 9)) << 16);

    // first-done step t* via ballot (no done checks in the hot loop)
    const unsigned long long mE = __ballot(d0 != 0);
    const unsigned long long mO = __ballot(d1 != 0);
    const int tE = mE ? 2 * __builtin_ctzll(mE)     : (1 << 30);
    const int tO = mO ? 2 * __builtin_ctzll(mO) + 1 : (1 << 30);
    const int tstar  = tE < tO ? tE : tO;
    const int nsteps = tstar < 128 ? tstar : 128;

    // regime==1 -> action term excluded every step: use RT table (a ignored)
    const bool skipA = (regime[b] == 1.0f);
    const int eBase = skipA ? L_RT : L_RA;
    const int eMulR = skipA ? 32 : 256;
    const int eMulA = skipA ? 0 : 32;

    float u = sE[L_PI + sl];
    int ksum = 0;
    float eoA, eraA, eoB, eraB;

    unsigned pkc = (unsigned)RLI(vpk, 0);
    unsigned pkn = (unsigned)RLI(vpk, 1);
    LOADE(eoA, eraA, pkc & 0xffffu);

    const int npairs = nsteps >> 1;
    #pragma unroll 1
    for (int i = 0; i < npairs; ++i) {
        // prefetch step 2i+1 (B), compute step 2i (A)
        LOADE(eoB, eraB, pkc >> 16);
        STEP(eoA, eraA, (int)((pkc >> 9) & 7u));
        // prefetch step 2i+2 (next A), compute step 2i+1 (B)
        LOADE(eoA, eraA, pkn & 0xffffu);
        STEP(eoB, eraB, (int)((pkc >> 25) & 7u));
        // rotate packed indices (readlane lane index wraps mod 64; overflow
        // reads are never consumed)
        pkc = pkn;
        pkn = (unsigned)RLI(vpk, i + 2);
        // exact power-of-two rescale every 2 steps (SALU exponent math)
        const int ub = RLI(__float_as_int(u), 0);
        const int kb = (ub >> 23) & 255;
        u *= __int_as_float((254 - kb) << 23);
        ksum += kb - 127;
    }

    if (nsteps & 1) {           // leftover even-index step (data already staged)
        STEP(eoA, eraA, (int)((pkc >> 9) & 7u));
    }

    // terminal contribution at e = min(t*, 128): OT*RT only (no action term)
    {
        const int e  = nsteps;
        const int oe = obs[e * B_N + b];
        const int re = rewards[e * B_N + b];
        const float eo = sE[L_OT + oe * 32 + sl];
        const float rt = sE[L_RT + re * 32 + sl];
        float t = u * eo * rt;
        t += __shfl_xor(t, 1, 32);
        t += __shfl_xor(t, 2, 32);
        t += __shfl_xor(t, 4, 32);
        t += __shfl_xor(t, 8, 32);
        t += __shfl_xor(t, 16, 32);
        const float result = (float)ksum * 0.69314718055994531f + __logf(t);
        if (lane == 0) out[b] = result;
    }
}

extern "C" void kernel_launch(void* const* d_in, const int* in_sizes, int n_in,
                              void* d_out, int out_size, void* d_ws, size_t ws_size,
                              hipStream_t stream) {
    (void)in_sizes; (void)n_in; (void)out_size; (void)ws_size;
    const float* regime      = (const float*)d_in[0];
    const int*   obs         = (const int*)d_in[1];
    const int*   rewards     = (const int*)d_in[2];
    const int*   dones_i     = (const int*)d_in[3];
    const int*   actions     = (const int*)d_in[4];
    const float* params_s    = (const float*)d_in[5];
    const float* params_s_sa = (const float*)d_in[6];
    const float* params_o_s  = (const float*)d_in[7];
    const float* params_r_s  = (const float*)d_in[8];
    const float* params_a_s  = (const float*)d_in[9];
    float* ws  = (float*)d_ws;
    float* out = (float*)d_out;

    tam_prep<<<2, 256, 0, stream>>>(params_s, params_s_sa, params_o_s,
                                    params_r_s, params_a_s, ws);
    tam_main<<<1024, 64, 0, stream>>>(regime, obs, rewards, dones_i, actions, ws, out);
}

// Round 6
// 47.616 us; speedup vs baseline: 1.3525x; 1.3525x over previous
//
#include <hip/hip_runtime.h>
#include <hip/hip_fp16.h>

// Problem constants (fixed by the reference)
#define S_N 32
#define O_N 64
#define A_N 8
#define R_N 8
#define B_N 1024
#define T_N 128

// Workspace layout (float-index offsets):
//  [0, 4096)      TH : packed fp16 transitions (16 KB), as uint4 entries
//                 entry[(a*4+q)*32 + sl] holds rows 8q..8q+7 of column sl:
//                 half j (0..7) of entry = Tr[8q+j][a][sl]
//  [4096, 6144)   OT[o][s]     = P(o|s)
//  [6144, 8192)   RA[r*8+a][s] = P(r|s)*P(a|s)
//  [8192, 8448)   RT[r][s]     = P(r|s)
//  [8448, 8480)   PI[s]
#define OT_OFF   4096
#define RA_OFF   6144
#define RT_OFF   8192
#define PI_OFF   8448

// LDS emission block (floats) — contiguous image of ws[4096..8480)
#define L_OT 0
#define L_RA 2048
#define L_RT 4096
#define L_PI 4352
#define L_N  4384

__global__ __launch_bounds__(256) void tam_prep(
    const float* __restrict__ params_s,
    const float* __restrict__ params_s_sa,
    const float* __restrict__ params_o_s,
    const float* __restrict__ params_r_s,
    const float* __restrict__ params_a_s,
    float* __restrict__ ws)
{
    const int tid = threadIdx.x;
    if (blockIdx.x == 0) {
        // Transitions: 256 threads, one (s,a) row softmax each; scatter fp16.
        const int s = tid >> 3, a = tid & 7;
        const float* row = params_s_sa + (s * A_N + a) * S_N;
        float p[32];
        #pragma unroll
        for (int i = 0; i < 8; ++i) {
            float4 v = reinterpret_cast<const float4*>(row)[i];
            p[4*i]=v.x; p[4*i+1]=v.y; p[4*i+2]=v.z; p[4*i+3]=v.w;
        }
        float mx = p[0];
        #pragma unroll
        for (int i = 1; i < 32; ++i) mx = fmaxf(mx, p[i]);
        float sum = 0.f;
        #pragma unroll
        for (int i = 0; i < 32; ++i) { p[i] = __expf(p[i] - mx); sum += p[i]; }
        const float inv = 1.0f / sum;
        // half index: ((a*4 + (s>>3))*32 + sl)*8 + (s&7)
        __half* wsh = reinterpret_cast<__half*>(ws);
        __half* base = wsh + (size_t)((a * 4 + (s >> 3)) * 32) * 8 + (s & 7);
        #pragma unroll
        for (int sl = 0; sl < 32; ++sl) base[sl * 8] = __float2half_rn(p[sl] * inv);
    } else {
        __shared__ float sRT[256], sAT[256];
        if (tid < 32) {
            // observation emission: softmax over O (64) per state; OT[o][s]
            const int s = tid;
            const float* row = params_o_s + s * O_N;
            float p[64];
            #pragma unroll
            for (int i = 0; i < 16; ++i) {
                float4 v = reinterpret_cast<const float4*>(row)[i];
                p[4*i]=v.x; p[4*i+1]=v.y; p[4*i+2]=v.z; p[4*i+3]=v.w;
            }
            float mx = p[0];
            #pragma unroll
            for (int i = 1; i < 64; ++i) mx = fmaxf(mx, p[i]);
            float sum = 0.f;
            #pragma unroll
            for (int i = 0; i < 64; ++i) { p[i] = __expf(p[i] - mx); sum += p[i]; }
            const float inv = 1.0f / sum;
            #pragma unroll
            for (int o = 0; o < 64; ++o) ws[OT_OFF + o * 32 + s] = p[o] * inv;
        } else if (tid < 64) {
            // reward emission: RT[r][s]
            const int s = tid - 32;
            const float* row = params_r_s + s * R_N;
            float p[8];
            #pragma unroll
            for (int i = 0; i < 2; ++i) {
                float4 v = reinterpret_cast<const float4*>(row)[i];
                p[4*i]=v.x; p[4*i+1]=v.y; p[4*i+2]=v.z; p[4*i+3]=v.w;
            }
            float mx = p[0];
            #pragma unroll
            for (int i = 1; i < 8; ++i) mx = fmaxf(mx, p[i]);
            float sum = 0.f;
            #pragma unroll
            for (int i = 0; i < 8; ++i) { p[i] = __expf(p[i] - mx); sum += p[i]; }
            const float inv = 1.0f / sum;
            #pragma unroll
            for (int r = 0; r < 8; ++r) {
                const float v = p[r] * inv;
                ws[RT_OFF + r * 32 + s] = v;
                sRT[r * 32 + s] = v;
            }
        } else if (tid < 96) {
            // action prior: AT[a][s] (LDS only, feeds RA)
            const int s = tid - 64;
            const float* row = params_a_s + s * A_N;
            float p[8];
            #pragma unroll
            for (int i = 0; i < 2; ++i) {
                float4 v = reinterpret_cast<const float4*>(row)[i];
                p[4*i]=v.x; p[4*i+1]=v.y; p[4*i+2]=v.z; p[4*i+3]=v.w;
            }
            float mx = p[0];
            #pragma unroll
            for (int i = 1; i < 8; ++i) mx = fmaxf(mx, p[i]);
            float sum = 0.f;
            #pragma unroll
            for (int i = 0; i < 8; ++i) { p[i] = __expf(p[i] - mx); sum += p[i]; }
            const float inv = 1.0f / sum;
            #pragma unroll
            for (int a = 0; a < 8; ++a) sAT[a * 32 + s] = p[a] * inv;
        } else if (tid < 128) {
            // pi = softmax(params_s): redundant compute, write own element
            const int s = tid - 96;
            float p[32];
            #pragma unroll
            for (int i = 0; i < 8; ++i) {
                float4 v = reinterpret_cast<const float4*>(params_s)[i];
                p[4*i]=v.x; p[4*i+1]=v.y; p[4*i+2]=v.z; p[4*i+3]=v.w;
            }
            float mx = p[0];
            #pragma unroll
            for (int i = 1; i < 32; ++i) mx = fmaxf(mx, p[i]);
            float sum = 0.f;
            #pragma unroll
            for (int i = 0; i < 32; ++i) { p[i] = __expf(p[i] - mx); sum += p[i]; }
            ws[PI_OFF + s] = p[s] / sum;
        }
        __syncthreads();
        // RA[r*8+a][s] = RT[r][s] * AT[a][s]
        #pragma unroll 1
        for (int i = tid; i < 2048; i += 256) {
            const int sl = i & 31, ra = i >> 5;
            ws[RA_OFF + i] = sRT[(ra >> 3) * 32 + sl] * sAT[(ra & 7) * 32 + sl];
        }
    }
}

#define RLI(v, l) __builtin_amdgcn_readlane((v), (l))
#define RLF(v, l) __int_as_float(__builtin_amdgcn_readlane(__float_as_int(v), (l)))

static __device__ __forceinline__ __half2 u2h(unsigned u) {
    union { unsigned u; __half2 h; } c; c.u = u; return c.h;
}

// Load action A_'s 32x32 fp16 transition column sl: 4 x ds_read_b128,
// address-indexed (NO branches). TH[k] = half2(row 2k, row 2k+1).
#define LOADTH(TH, A_) {                                                     \
    const uint4* p_ = sTH + ((A_) << 7) + sl;                                \
    const uint4 q0_ = p_[0], q1_ = p_[32], q2_ = p_[64], q3_ = p_[96];       \
    TH[0]=q0_.x;  TH[1]=q0_.y;  TH[2]=q0_.z;  TH[3]=q0_.w;                   \
    TH[4]=q1_.x;  TH[5]=q1_.y;  TH[6]=q1_.z;  TH[7]=q1_.w;                   \
    TH[8]=q2_.x;  TH[9]=q2_.y;  TH[10]=q2_.z; TH[11]=q2_.w;                  \
    TH[12]=q3_.x; TH[13]=q3_.y; TH[14]=q3_.z; TH[15]=q3_.w; }

// Emission factors for the step encoded in the low 16 bits of PKW (from LDS)
#define LOADE(EO, ERA, PKW) {                                                \
    const unsigned pk_ = (PKW);                                              \
    EO  = sE[(int)(pk_ & 63u) * 32 + sl];                                    \
    ERA = sE[eBase + (int)((pk_ >> 6) & 7u) * eMulR                          \
                   + (int)((pk_ >> 9) & 7u) * eMulA + sl]; }

// One HMM step: w = u .* e ; u' = T_a^T w  (32 readlane broadcasts + 32
// mixed-precision fmas against the staged TH regs; 4 accumulator chains)
#define STEP(EO, ERA, TH) {                                                  \
    const float wv = u * (EO) * (ERA);                                       \
    const float w0 =RLF(wv,0),  w1 =RLF(wv,1),  w2 =RLF(wv,2),  w3 =RLF(wv,3),  \
                w4 =RLF(wv,4),  w5 =RLF(wv,5),  w6 =RLF(wv,6),  w7 =RLF(wv,7),  \
                w8 =RLF(wv,8),  w9 =RLF(wv,9),  w10=RLF(wv,10), w11=RLF(wv,11), \
                w12=RLF(wv,12), w13=RLF(wv,13), w14=RLF(wv,14), w15=RLF(wv,15), \
                w16=RLF(wv,16), w17=RLF(wv,17), w18=RLF(wv,18), w19=RLF(wv,19), \
                w20=RLF(wv,20), w21=RLF(wv,21), w22=RLF(wv,22), w23=RLF(wv,23), \
                w24=RLF(wv,24), w25=RLF(wv,25), w26=RLF(wv,26), w27=RLF(wv,27), \
                w28=RLF(wv,28), w29=RLF(wv,29), w30=RLF(wv,30), w31=RLF(wv,31); \
    float c0 = 0.f, c1 = 0.f, c2 = 0.f, c3 = 0.f;                            \
    c0=fmaf(w0, __low2float(u2h(TH[0])), c0); c1=fmaf(w1, __high2float(u2h(TH[0])), c1); \
    c2=fmaf(w2, __low2float(u2h(TH[1])), c2); c3=fmaf(w3, __high2float(u2h(TH[1])), c3); \
    c0=fmaf(w4, __low2float(u2h(TH[2])), c0); c1=fmaf(w5, __high2float(u2h(TH[2])), c1); \
    c2=fmaf(w6, __low2float(u2h(TH[3])), c2); c3=fmaf(w7, __high2float(u2h(TH[3])), c3); \
    c0=fmaf(w8, __low2float(u2h(TH[4])), c0); c1=fmaf(w9, __high2float(u2h(TH[4])), c1); \
    c2=fmaf(w10,__low2float(u2h(TH[5])), c2); c3=fmaf(w11,__high2float(u2h(TH[5])), c3); \
    c0=fmaf(w12,__low2float(u2h(TH[6])), c0); c1=fmaf(w13,__high2float(u2h(TH[6])), c1); \
    c2=fmaf(w14,__low2float(u2h(TH[7])), c2); c3=fmaf(w15,__high2float(u2h(TH[7])), c3); \
    c0=fmaf(w16,__low2float(u2h(TH[8])), c0); c1=fmaf(w17,__high2float(u2h(TH[8])), c1); \
    c2=fmaf(w18,__low2float(u2h(TH[9])), c2); c3=fmaf(w19,__high2float(u2h(TH[9])), c3); \
    c0=fmaf(w20,__low2float(u2h(TH[10])),c0); c1=fmaf(w21,__high2float(u2h(TH[10])),c1); \
    c2=fmaf(w22,__low2float(u2h(TH[11])),c2); c3=fmaf(w23,__high2float(u2h(TH[11])),c3); \
    c0=fmaf(w24,__low2float(u2h(TH[12])),c0); c1=fmaf(w25,__high2float(u2h(TH[12])),c1); \
    c2=fmaf(w26,__low2float(u2h(TH[13])),c2); c3=fmaf(w27,__high2float(u2h(TH[13])),c3); \
    c0=fmaf(w28,__low2float(u2h(TH[14])),c0); c1=fmaf(w29,__high2float(u2h(TH[14])),c1); \
    c2=fmaf(w30,__low2float(u2h(TH[15])),c2); c3=fmaf(w31,__high2float(u2h(TH[15])),c3); \
    u = (c0 + c1) + (c2 + c3); }

// One wave (64 lanes) per episode. lane&31 = destination state s' (halves
// replicated). T fp16-packed in LDS (address-indexed, 4 b128/step),
// emissions in LDS; both prefetched one step ahead. Zero branches in loop.
__global__ __launch_bounds__(64, 1) void tam_main(
    const float* __restrict__ regime,
    const int*   __restrict__ obs,
    const int*   __restrict__ rewards,
    const int*   __restrict__ dones_i,   // float32 0/1 read as int bits
    const int*   __restrict__ actions,
    const float* __restrict__ ws,
    float* __restrict__ out)
{
    __shared__ uint4 sTH[1024];          // 16 KB packed fp16 transitions
    __shared__ float sE[L_N];            // 17.1 KB emission block
    const int lane = threadIdx.x;
    const int sl   = lane & 31;
    const int b    = blockIdx.x;

    // stage T (16 KB) and emissions (17.1 KB) into LDS — coalesced copies
    {
        const uint4* gt = reinterpret_cast<const uint4*>(ws);
        #pragma unroll
        for (int i = 0; i < 16; ++i) sTH[lane + i * 64] = gt[lane + i * 64];
        const float4* ge = reinterpret_cast<const float4*>(ws + OT_OFF);
        float4* s4 = reinterpret_cast<float4*>(sE);
        #pragma unroll 1
        for (int i = lane; i < L_N / 4; i += 64) s4[i] = ge[i];
    }
    __syncthreads();

    // per-lane packed step-pair indices: lane i holds steps 2i (low16), 2i+1 (high16)
    const int t0 = 2 * lane, t1 = 2 * lane + 1;
    const int o0 = obs[t0 * B_N + b],      o1 = obs[t1 * B_N + b];
    const int r0 = rewards[t0 * B_N + b],  r1 = rewards[t1 * B_N + b];
    const int a0 = actions[t0 * B_N + b],  a1 = actions[t1 * B_N + b];
    const int d0 = dones_i[t0 * B_N + b],  d1 = dones_i[t1 * B_N + b];
    const int vpk = (o0 | (r0 << 6) | (a0 << 9)) |
                    ((o1 | (r1 << 6) | (a1 << 9)) << 16);

    // first-done step t* via ballot (no done checks in the hot loop)
    const unsigned long long mE = __ballot(d0 != 0);
    const unsigned long long mO = __ballot(d1 != 0);
    const int tE = mE ? 2 * __builtin_ctzll(mE)     : (1 << 30);
    const int tO = mO ? 2 * __builtin_ctzll(mO) + 1 : (1 << 30);
    const int tstar  = tE < tO ? tE : tO;
    const int nsteps = tstar < 128 ? tstar : 128;

    // regime==1 -> action term excluded every step: use RT table (a ignored)
    const bool skipA = (regime[b] == 1.0f);
    const int eBase = skipA ? L_RT : L_RA;
    const int eMulR = skipA ? 32 : 256;
    const int eMulA = skipA ? 0 : 32;

    float u = sE[L_PI + sl];
    int ksum = 0;
    float eoA, eraA, eoB, eraB;
    unsigned thA[16], thB[16];

    unsigned pkc = (unsigned)RLI(vpk, 0);
    unsigned pkn = (unsigned)RLI(vpk, 1);
    LOADE(eoA, eraA, pkc & 0xffffu);
    LOADTH(thA, (int)((pkc >> 9) & 7u));

    const int npairs = nsteps >> 1;
    #pragma unroll 1
    for (int i = 0; i < npairs; ++i) {
        // prefetch step 2i+1 (B), compute step 2i (A)
        LOADE(eoB, eraB, pkc >> 16);
        LOADTH(thB, (int)((pkc >> 25) & 7u));
        STEP(eoA, eraA, thA);
        // prefetch step 2i+2 (next A), compute step 2i+1 (B)
        LOADE(eoA, eraA, pkn & 0xffffu);
        LOADTH(thA, (int)((pkn >> 9) & 7u));
        STEP(eoB, eraB, thB);
        // rotate packed indices (readlane lane wraps mod 64; overflow unused)
        pkc = pkn;
        pkn = (unsigned)RLI(vpk, i + 2);
        // exact power-of-two rescale every 2 steps (SALU exponent math)
        const int ub = RLI(__float_as_int(u), 0);
        const int kb = (ub >> 23) & 255;
        u *= __int_as_float((254 - kb) << 23);
        ksum += kb - 127;
    }

    if (nsteps & 1) {           // leftover even-index step (data already staged)
        STEP(eoA, eraA, thA);
    }

    // terminal contribution at e = min(t*, 128): OT*RT only (no action term)
    {
        const int e  = nsteps;
        const int oe = obs[e * B_N + b];
        const int re = rewards[e * B_N + b];
        const float eo = sE[L_OT + oe * 32 + sl];
        const float rt = sE[L_RT + re * 32 + sl];
        float t = u * eo * rt;
        t += __shfl_xor(t, 1, 32);
        t += __shfl_xor(t, 2, 32);
        t += __shfl_xor(t, 4, 32);
        t += __shfl_xor(t, 8, 32);
        t += __shfl_xor(t, 16, 32);
        const float result = (float)ksum * 0.69314718055994531f + __logf(t);
        if (lane == 0) out[b] = result;
    }
}

extern "C" void kernel_launch(void* const* d_in, const int* in_sizes, int n_in,
                              void* d_out, int out_size, void* d_ws, size_t ws_size,
                              hipStream_t stream) {
    (void)in_sizes; (void)n_in; (void)out_size; (void)ws_size;
    const float* regime      = (const float*)d_in[0];
    const int*   obs         = (const int*)d_in[1];
    const int*   rewards     = (const int*)d_in[2];
    const int*   dones_i     = (const int*)d_in[3];
    const int*   actions     = (const int*)d_in[4];
    const float* params_s    = (const float*)d_in[5];
    const float* params_s_sa = (const float*)d_in[6];
    const float* params_o_s  = (const float*)d_in[7];
    const float* params_r_s  = (const float*)d_in[8];
    const float* params_a_s  = (const float*)d_in[9];
    float* ws  = (float*)d_ws;
    float* out = (float*)d_out;

    tam_prep<<<2, 256, 0, stream>>>(params_s, params_s_sa, params_o_s,
                                    params_r_s, params_a_s, ws);
    tam_main<<<1024, 64, 0, stream>>>(regime, obs, rewards, dones_i, actions, ws, out);
}

// Round 7
// 44.379 us; speedup vs baseline: 1.4511x; 1.0729x over previous
//
#include <hip/hip_runtime.h>
#include <hip/hip_fp16.h>

// Problem constants (fixed by the reference)
#define S_N 32
#define O_N 64
#define A_N 8
#define R_N 8
#define B_N 1024
#define T_N 128

// Workspace layout (float-index offsets):
//  [0, 4096)      TH : packed fp16 transitions (16 KB), as uint4 entries
//                 entry[(a*4+q)*32 + sl] holds rows 8q..8q+7 of column sl:
//                 half j (0..7) of entry = Tr[8q+j][a][sl]
//  [4096, 6144)   OT[o][s]     = P(o|s)
//  [6144, 8192)   RA[r*8+a][s] = P(r|s)*P(a|s)
//  [8192, 8448)   RT[r][s]     = P(r|s)
//  [8448, 8480)   PI[s]
#define OT_OFF   4096
#define RA_OFF   6144
#define RT_OFF   8192
#define PI_OFF   8448

// LDS emission block (floats) — contiguous image of ws[4096..8480)
#define L_OT 0
#define L_RA 2048
#define L_RT 4096
#define L_PI 4352
#define L_N  4384

__global__ __launch_bounds__(256) void tam_prep(
    const float* __restrict__ params_s,
    const float* __restrict__ params_s_sa,
    const float* __restrict__ params_o_s,
    const float* __restrict__ params_r_s,
    const float* __restrict__ params_a_s,
    float* __restrict__ ws)
{
    const int tid = threadIdx.x;
    if (blockIdx.x == 0) {
        // Transitions: 256 threads, one (s,a) row softmax each; scatter fp16.
        const int s = tid >> 3, a = tid & 7;
        const float* row = params_s_sa + (s * A_N + a) * S_N;
        float p[32];
        #pragma unroll
        for (int i = 0; i < 8; ++i) {
            float4 v = reinterpret_cast<const float4*>(row)[i];
            p[4*i]=v.x; p[4*i+1]=v.y; p[4*i+2]=v.z; p[4*i+3]=v.w;
        }
        float mx = p[0];
        #pragma unroll
        for (int i = 1; i < 32; ++i) mx = fmaxf(mx, p[i]);
        float sum = 0.f;
        #pragma unroll
        for (int i = 0; i < 32; ++i) { p[i] = __expf(p[i] - mx); sum += p[i]; }
        const float inv = 1.0f / sum;
        // half index: ((a*4 + (s>>3))*32 + sl)*8 + (s&7)
        __half* wsh = reinterpret_cast<__half*>(ws);
        __half* base = wsh + (size_t)((a * 4 + (s >> 3)) * 32) * 8 + (s & 7);
        #pragma unroll
        for (int sl = 0; sl < 32; ++sl) base[sl * 8] = __float2half_rn(p[sl] * inv);
    } else {
        __shared__ float sRT[256], sAT[256];
        if (tid < 32) {
            // observation emission: softmax over O (64) per state; OT[o][s]
            const int s = tid;
            const float* row = params_o_s + s * O_N;
            float p[64];
            #pragma unroll
            for (int i = 0; i < 16; ++i) {
                float4 v = reinterpret_cast<const float4*>(row)[i];
                p[4*i]=v.x; p[4*i+1]=v.y; p[4*i+2]=v.z; p[4*i+3]=v.w;
            }
            float mx = p[0];
            #pragma unroll
            for (int i = 1; i < 64; ++i) mx = fmaxf(mx, p[i]);
            float sum = 0.f;
            #pragma unroll
            for (int i = 0; i < 64; ++i) { p[i] = __expf(p[i] - mx); sum += p[i]; }
            const float inv = 1.0f / sum;
            #pragma unroll
            for (int o = 0; o < 64; ++o) ws[OT_OFF + o * 32 + s] = p[o] * inv;
        } else if (tid < 64) {
            // reward emission: RT[r][s]
            const int s = tid - 32;
            const float* row = params_r_s + s * R_N;
            float p[8];
            #pragma unroll
            for (int i = 0; i < 2; ++i) {
                float4 v = reinterpret_cast<const float4*>(row)[i];
                p[4*i]=v.x; p[4*i+1]=v.y; p[4*i+2]=v.z; p[4*i+3]=v.w;
            }
            float mx = p[0];
            #pragma unroll
            for (int i = 1; i < 8; ++i) mx = fmaxf(mx, p[i]);
            float sum = 0.f;
            #pragma unroll
            for (int i = 0; i < 8; ++i) { p[i] = __expf(p[i] - mx); sum += p[i]; }
            const float inv = 1.0f / sum;
            #pragma unroll
            for (int r = 0; r < 8; ++r) {
                const float v = p[r] * inv;
                ws[RT_OFF + r * 32 + s] = v;
                sRT[r * 32 + s] = v;
            }
        } else if (tid < 96) {
            // action prior: AT[a][s] (LDS only, feeds RA)
            const int s = tid - 64;
            const float* row = params_a_s + s * A_N;
            float p[8];
            #pragma unroll
            for (int i = 0; i < 2; ++i) {
                float4 v = reinterpret_cast<const float4*>(row)[i];
                p[4*i]=v.x; p[4*i+1]=v.y; p[4*i+2]=v.z; p[4*i+3]=v.w;
            }
            float mx = p[0];
            #pragma unroll
            for (int i = 1; i < 8; ++i) mx = fmaxf(mx, p[i]);
            float sum = 0.f;
            #pragma unroll
            for (int i = 0; i < 8; ++i) { p[i] = __expf(p[i] - mx); sum += p[i]; }
            const float inv = 1.0f / sum;
            #pragma unroll
            for (int a = 0; a < 8; ++a) sAT[a * 32 + s] = p[a] * inv;
        } else if (tid < 128) {
            // pi = softmax(params_s): redundant compute, write own element
            const int s = tid - 96;
            float p[32];
            #pragma unroll
            for (int i = 0; i < 8; ++i) {
                float4 v = reinterpret_cast<const float4*>(params_s)[i];
                p[4*i]=v.x; p[4*i+1]=v.y; p[4*i+2]=v.z; p[4*i+3]=v.w;
            }
            float mx = p[0];
            #pragma unroll
            for (int i = 1; i < 32; ++i) mx = fmaxf(mx, p[i]);
            float sum = 0.f;
            #pragma unroll
            for (int i = 0; i < 32; ++i) { p[i] = __expf(p[i] - mx); sum += p[i]; }
            ws[PI_OFF + s] = p[s] / sum;
        }
        __syncthreads();
        // RA[r*8+a][s] = RT[r][s] * AT[a][s]
        #pragma unroll 1
        for (int i = tid; i < 2048; i += 256) {
            const int sl = i & 31, ra = i >> 5;
            ws[RA_OFF + i] = sRT[(ra >> 3) * 32 + sl] * sAT[(ra & 7) * 32 + sl];
        }
    }
}

#define RLI(v, l) __builtin_amdgcn_readlane((v), (l))
#define RLF(v, l) __int_as_float(__builtin_amdgcn_readlane(__float_as_int(v), (l)))

static __device__ __forceinline__ __half2 u2h(unsigned u) {
    union { unsigned u; __half2 h; } c; c.u = u; return c.h;
}

// Load action A_'s 32x32 fp16 transition column sl: 4 x ds_read_b128,
// address-indexed (NO branches). TH[k] = half2(row 2k, row 2k+1).
#define LOADTH(TH, A_) {                                                     \
    const uint4* p_ = sTH + ((A_) << 7) + sl;                                \
    const uint4 q0_ = p_[0], q1_ = p_[32], q2_ = p_[64], q3_ = p_[96];       \
    TH[0]=q0_.x;  TH[1]=q0_.y;  TH[2]=q0_.z;  TH[3]=q0_.w;                   \
    TH[4]=q1_.x;  TH[5]=q1_.y;  TH[6]=q1_.z;  TH[7]=q1_.w;                   \
    TH[8]=q2_.x;  TH[9]=q2_.y;  TH[10]=q2_.z; TH[11]=q2_.w;                  \
    TH[12]=q3_.x; TH[13]=q3_.y; TH[14]=q3_.z; TH[15]=q3_.w; }

// Emission factors for the step encoded in the low 16 bits of PKW (from LDS)
#define LOADE(EO, ERA, PKW) {                                                \
    const unsigned pk_ = (PKW);                                              \
    EO  = sE[(int)(pk_ & 63u) * 32 + sl];                                    \
    ERA = sE[eBase + (int)((pk_ >> 6) & 7u) * eMulR                          \
                   + (int)((pk_ >> 9) & 7u) * eMulA + sl]; }

// One HMM step: w = u .* e ; u' = T_a^T w  (32 readlane broadcasts + 32
// mixed-precision fmas against the staged TH regs; 4 accumulator chains)
#define STEP(EO, ERA, TH) {                                                  \
    const float wv = u * (EO) * (ERA);                                       \
    const float w0 =RLF(wv,0),  w1 =RLF(wv,1),  w2 =RLF(wv,2),  w3 =RLF(wv,3),  \
                w4 =RLF(wv,4),  w5 =RLF(wv,5),  w6 =RLF(wv,6),  w7 =RLF(wv,7),  \
                w8 =RLF(wv,8),  w9 =RLF(wv,9),  w10=RLF(wv,10), w11=RLF(wv,11), \
                w12=RLF(wv,12), w13=RLF(wv,13), w14=RLF(wv,14), w15=RLF(wv,15), \
                w16=RLF(wv,16), w17=RLF(wv,17), w18=RLF(wv,18), w19=RLF(wv,19), \
                w20=RLF(wv,20), w21=RLF(wv,21), w22=RLF(wv,22), w23=RLF(wv,23), \
                w24=RLF(wv,24), w25=RLF(wv,25), w26=RLF(wv,26), w27=RLF(wv,27), \
                w28=RLF(wv,28), w29=RLF(wv,29), w30=RLF(wv,30), w31=RLF(wv,31); \
    float c0 = 0.f, c1 = 0.f, c2 = 0.f, c3 = 0.f;                            \
    c0=fmaf(w0, __low2float(u2h(TH[0])), c0); c1=fmaf(w1, __high2float(u2h(TH[0])), c1); \
    c2=fmaf(w2, __low2float(u2h(TH[1])), c2); c3=fmaf(w3, __high2float(u2h(TH[1])), c3); \
    c0=fmaf(w4, __low2float(u2h(TH[2])), c0); c1=fmaf(w5, __high2float(u2h(TH[2])), c1); \
    c2=fmaf(w6, __low2float(u2h(TH[3])), c2); c3=fmaf(w7, __high2float(u2h(TH[3])), c3); \
    c0=fmaf(w8, __low2float(u2h(TH[4])), c0); c1=fmaf(w9, __high2float(u2h(TH[4])), c1); \
    c2=fmaf(w10,__low2float(u2h(TH[5])), c2); c3=fmaf(w11,__high2float(u2h(TH[5])), c3); \
    c0=fmaf(w12,__low2float(u2h(TH[6])), c0); c1=fmaf(w13,__high2float(u2h(TH[6])), c1); \
    c2=fmaf(w14,__low2float(u2h(TH[7])), c2); c3=fmaf(w15,__high2float(u2h(TH[7])), c3); \
    c0=fmaf(w16,__low2float(u2h(TH[8])), c0); c1=fmaf(w17,__high2float(u2h(TH[8])), c1); \
    c2=fmaf(w18,__low2float(u2h(TH[9])), c2); c3=fmaf(w19,__high2float(u2h(TH[9])), c3); \
    c0=fmaf(w20,__low2float(u2h(TH[10])),c0); c1=fmaf(w21,__high2float(u2h(TH[10])),c1); \
    c2=fmaf(w22,__low2float(u2h(TH[11])),c2); c3=fmaf(w23,__high2float(u2h(TH[11])),c3); \
    c0=fmaf(w24,__low2float(u2h(TH[12])),c0); c1=fmaf(w25,__high2float(u2h(TH[12])),c1); \
    c2=fmaf(w26,__low2float(u2h(TH[13])),c2); c3=fmaf(w27,__high2float(u2h(TH[13])),c3); \
    c0=fmaf(w28,__low2float(u2h(TH[14])),c0); c1=fmaf(w29,__high2float(u2h(TH[14])),c1); \
    c2=fmaf(w30,__low2float(u2h(TH[15])),c2); c3=fmaf(w31,__high2float(u2h(TH[15])),c3); \
    u = (c0 + c1) + (c2 + c3); }

// 4 waves per block, ONE episode per wave, shared LDS tables. 16 waves/CU =
// 4 independent chains per SIMD -> TLP hides the per-chain stalls that
// dominated the 1-wave/SIMD versions. Hot loop identical to round 6.
__global__ __launch_bounds__(256, 4) void tam_main(
    const float* __restrict__ regime,
    const int*   __restrict__ obs,
    const int*   __restrict__ rewards,
    const int*   __restrict__ dones_i,   // float32 0/1 read as int bits
    const int*   __restrict__ actions,
    const float* __restrict__ ws,
    float* __restrict__ out)
{
    __shared__ uint4 sTH[1024];          // 16 KB packed fp16 transitions
    __shared__ float sE[L_N];            // 17.1 KB emission block
    const int tid  = threadIdx.x;
    const int lane = tid & 63;
    const int wid  = tid >> 6;
    const int sl   = lane & 31;
    const int b    = blockIdx.x * 4 + wid;

    // stage T (16 KB) and emissions (17.1 KB) into LDS — 256 threads
    {
        const uint4* gt = reinterpret_cast<const uint4*>(ws);
        #pragma unroll
        for (int i = 0; i < 4; ++i) sTH[tid + i * 256] = gt[tid + i * 256];
        const float4* ge = reinterpret_cast<const float4*>(ws + OT_OFF);
        float4* s4 = reinterpret_cast<float4*>(sE);
        #pragma unroll 1
        for (int i = tid; i < L_N / 4; i += 256) s4[i] = ge[i];
    }
    __syncthreads();

    // per-lane packed step-pair indices: lane i holds steps 2i (low16), 2i+1 (high16)
    const int t0 = 2 * lane, t1 = 2 * lane + 1;
    const int o0 = obs[t0 * B_N + b],      o1 = obs[t1 * B_N + b];
    const int r0 = rewards[t0 * B_N + b],  r1 = rewards[t1 * B_N + b];
    const int a0 = actions[t0 * B_N + b],  a1 = actions[t1 * B_N + b];
    const int d0 = dones_i[t0 * B_N + b],  d1 = dones_i[t1 * B_N + b];
    const int vpk = (o0 | (r0 << 6) | (a0 << 9)) |
                    ((o1 | (r1 << 6) | (a1 << 9)) << 16);

    // first-done step t* via ballot (per-wave; no done checks in the hot loop)
    const unsigned long long mE = __ballot(d0 != 0);
    const unsigned long long mO = __ballot(d1 != 0);
    const int tE = mE ? 2 * __builtin_ctzll(mE)     : (1 << 30);
    const int tO = mO ? 2 * __builtin_ctzll(mO) + 1 : (1 << 30);
    const int tstar  = tE < tO ? tE : tO;
    const int nsteps = tstar < 128 ? tstar : 128;

    // regime==1 -> action term excluded every step: use RT table (a ignored)
    const bool skipA = (regime[b] == 1.0f);
    const int eBase = skipA ? L_RT : L_RA;
    const int eMulR = skipA ? 32 : 256;
    const int eMulA = skipA ? 0 : 32;

    float u = sE[L_PI + sl];
    int ksum = 0;
    float eoA, eraA, eoB, eraB;
    unsigned thA[16], thB[16];

    unsigned pkc = (unsigned)RLI(vpk, 0);
    unsigned pkn = (unsigned)RLI(vpk, 1);
    LOADE(eoA, eraA, pkc & 0xffffu);
    LOADTH(thA, (int)((pkc >> 9) & 7u));

    const int npairs = nsteps >> 1;
    #pragma unroll 1
    for (int i = 0; i < npairs; ++i) {
        // prefetch step 2i+1 (B), compute step 2i (A)
        LOADE(eoB, eraB, pkc >> 16);
        LOADTH(thB, (int)((pkc >> 25) & 7u));
        STEP(eoA, eraA, thA);
        // prefetch step 2i+2 (next A), compute step 2i+1 (B)
        LOADE(eoA, eraA, pkn & 0xffffu);
        LOADTH(thA, (int)((pkn >> 9) & 7u));
        STEP(eoB, eraB, thB);
        // rotate packed indices (readlane lane wraps mod 64; overflow unused)
        pkc = pkn;
        pkn = (unsigned)RLI(vpk, i + 2);
        // exact power-of-two rescale every 2 steps (SALU exponent math)
        const int ub = RLI(__float_as_int(u), 0);
        const int kb = (ub >> 23) & 255;
        u *= __int_as_float((254 - kb) << 23);
        ksum += kb - 127;
    }

    if (nsteps & 1) {           // leftover even-index step (data already staged)
        STEP(eoA, eraA, thA);
    }

    // terminal contribution at e = min(t*, 128): OT*RT only (no action term)
    {
        const int e  = nsteps;
        const int oe = obs[e * B_N + b];
        const int re = rewards[e * B_N + b];
        const float eo = sE[L_OT + oe * 32 + sl];
        const float rt = sE[L_RT + re * 32 + sl];
        float t = u * eo * rt;
        t += __shfl_xor(t, 1, 32);
        t += __shfl_xor(t, 2, 32);
        t += __shfl_xor(t, 4, 32);
        t += __shfl_xor(t, 8, 32);
        t += __shfl_xor(t, 16, 32);
        const float result = (float)ksum * 0.69314718055994531f + __logf(t);
        if (lane == 0) out[b] = result;
    }
}

extern "C" void kernel_launch(void* const* d_in, const int* in_sizes, int n_in,
                              void* d_out, int out_size, void* d_ws, size_t ws_size,
                              hipStream_t stream) {
    (void)in_sizes; (void)n_in; (void)out_size; (void)ws_size;
    const float* regime      = (const float*)d_in[0];
    const int*   obs         = (const int*)d_in[1];
    const int*   rewards     = (const int*)d_in[2];
    const int*   dones_i     = (const int*)d_in[3];
    const int*   actions     = (const int*)d_in[4];
    const float* params_s    = (const float*)d_in[5];
    const float* params_s_sa = (const float*)d_in[6];
    const float* params_o_s  = (const float*)d_in[7];
    const float* params_r_s  = (const float*)d_in[8];
    const float* params_a_s  = (const float*)d_in[9];
    float* ws  = (float*)d_ws;
    float* out = (float*)d_out;

    tam_prep<<<2, 256, 0, stream>>>(params_s, params_s_sa, params_o_s,
                                    params_r_s, params_a_s, ws);
    tam_main<<<256, 256, 0, stream>>>(regime, obs, rewards, dones_i, actions, ws, out);
}

// Round 8
// 41.124 us; speedup vs baseline: 1.5660x; 1.0792x over previous
//
#include <hip/hip_runtime.h>
#include <hip/hip_fp16.h>

// Problem constants (fixed by the reference)
#define S_N 32
#define O_N 64
#define A_N 8
#define R_N 8
#define B_N 1024
#define T_N 128

// Workspace layout (float-index offsets):
//  [0, 4096)      TH : packed fp16 transitions (16 KB), as uint4 entries
//                 entry[(a*4+q)*32 + sl] holds rows 8q..8q+7 of column sl
//  [4096, 6144)   OT[o][s]     = P(o|s)
//  [6144, 8192)   RA[r*8+a][s] = P(r|s)*P(a|s)
//  [8192, 8448)   RT[r][s]     = P(r|s)
//  [8448, 8480)   PI[s]
#define OT_OFF   4096
#define RA_OFF   6144
#define RT_OFF   8192
#define PI_OFF   8448

// LDS emission block (floats) — contiguous image of ws[4096..8480)
#define L_OT 0
#define L_RA 2048
#define L_RT 4096
#define L_PI 4352
#define L_N  4384

__global__ __launch_bounds__(256) void tam_prep(
    const float* __restrict__ params_s,
    const float* __restrict__ params_s_sa,
    const float* __restrict__ params_o_s,
    const float* __restrict__ params_r_s,
    const float* __restrict__ params_a_s,
    float* __restrict__ ws)
{
    const int tid = threadIdx.x;
    if (blockIdx.x == 0) {
        // Transitions: 256 threads, one (s,a) row softmax each; scatter fp16.
        const int s = tid >> 3, a = tid & 7;
        const float* row = params_s_sa + (s * A_N + a) * S_N;
        float p[32];
        #pragma unroll
        for (int i = 0; i < 8; ++i) {
            float4 v = reinterpret_cast<const float4*>(row)[i];
            p[4*i]=v.x; p[4*i+1]=v.y; p[4*i+2]=v.z; p[4*i+3]=v.w;
        }
        float mx = p[0];
        #pragma unroll
        for (int i = 1; i < 32; ++i) mx = fmaxf(mx, p[i]);
        float sum = 0.f;
        #pragma unroll
        for (int i = 0; i < 32; ++i) { p[i] = __expf(p[i] - mx); sum += p[i]; }
        const float inv = 1.0f / sum;
        // half index: ((a*4 + (s>>3))*32 + sl)*8 + (s&7)
        __half* wsh = reinterpret_cast<__half*>(ws);
        __half* base = wsh + (size_t)((a * 4 + (s >> 3)) * 32) * 8 + (s & 7);
        #pragma unroll
        for (int sl = 0; sl < 32; ++sl) base[sl * 8] = __float2half_rn(p[sl] * inv);
    } else {
        __shared__ float sRT[256], sAT[256];
        if (tid < 32) {
            // observation emission: softmax over O (64) per state; OT[o][s]
            const int s = tid;
            const float* row = params_o_s + s * O_N;
            float p[64];
            #pragma unroll
            for (int i = 0; i < 16; ++i) {
                float4 v = reinterpret_cast<const float4*>(row)[i];
                p[4*i]=v.x; p[4*i+1]=v.y; p[4*i+2]=v.z; p[4*i+3]=v.w;
            }
            float mx = p[0];
            #pragma unroll
            for (int i = 1; i < 64; ++i) mx = fmaxf(mx, p[i]);
            float sum = 0.f;
            #pragma unroll
            for (int i = 0; i < 64; ++i) { p[i] = __expf(p[i] - mx); sum += p[i]; }
            const float inv = 1.0f / sum;
            #pragma unroll
            for (int o = 0; o < 64; ++o) ws[OT_OFF + o * 32 + s] = p[o] * inv;
        } else if (tid < 64) {
            // reward emission: RT[r][s]
            const int s = tid - 32;
            const float* row = params_r_s + s * R_N;
            float p[8];
            #pragma unroll
            for (int i = 0; i < 2; ++i) {
                float4 v = reinterpret_cast<const float4*>(row)[i];
                p[4*i]=v.x; p[4*i+1]=v.y; p[4*i+2]=v.z; p[4*i+3]=v.w;
            }
            float mx = p[0];
            #pragma unroll
            for (int i = 1; i < 8; ++i) mx = fmaxf(mx, p[i]);
            float sum = 0.f;
            #pragma unroll
            for (int i = 0; i < 8; ++i) { p[i] = __expf(p[i] - mx); sum += p[i]; }
            const float inv = 1.0f / sum;
            #pragma unroll
            for (int r = 0; r < 8; ++r) {
                const float v = p[r] * inv;
                ws[RT_OFF + r * 32 + s] = v;
                sRT[r * 32 + s] = v;
            }
        } else if (tid < 96) {
            // action prior: AT[a][s] (LDS only, feeds RA)
            const int s = tid - 64;
            const float* row = params_a_s + s * A_N;
            float p[8];
            #pragma unroll
            for (int i = 0; i < 2; ++i) {
                float4 v = reinterpret_cast<const float4*>(row)[i];
                p[4*i]=v.x; p[4*i+1]=v.y; p[4*i+2]=v.z; p[4*i+3]=v.w;
            }
            float mx = p[0];
            #pragma unroll
            for (int i = 1; i < 8; ++i) mx = fmaxf(mx, p[i]);
            float sum = 0.f;
            #pragma unroll
            for (int i = 0; i < 8; ++i) { p[i] = __expf(p[i] - mx); sum += p[i]; }
            const float inv = 1.0f / sum;
            #pragma unroll
            for (int a = 0; a < 8; ++a) sAT[a * 32 + s] = p[a] * inv;
        } else if (tid < 128) {
            // pi = softmax(params_s): redundant compute, write own element
            const int s = tid - 96;
            float p[32];
            #pragma unroll
            for (int i = 0; i < 8; ++i) {
                float4 v = reinterpret_cast<const float4*>(params_s)[i];
                p[4*i]=v.x; p[4*i+1]=v.y; p[4*i+2]=v.z; p[4*i+3]=v.w;
            }
            float mx = p[0];
            #pragma unroll
            for (int i = 1; i < 32; ++i) mx = fmaxf(mx, p[i]);
            float sum = 0.f;
            #pragma unroll
            for (int i = 0; i < 32; ++i) { p[i] = __expf(p[i] - mx); sum += p[i]; }
            ws[PI_OFF + s] = p[s] / sum;
        }
        __syncthreads();
        // RA[r*8+a][s] = RT[r][s] * AT[a][s]
        #pragma unroll 1
        for (int i = tid; i < 2048; i += 256) {
            const int sl = i & 31, ra = i >> 5;
            ws[RA_OFF + i] = sRT[(ra >> 3) * 32 + sl] * sAT[(ra & 7) * 32 + sl];
        }
    }
}

#define RLI(v, l) __builtin_amdgcn_readlane((v), (l))
#define RLF(v, l) __int_as_float(__builtin_amdgcn_readlane(__float_as_int(v), (l)))

static __device__ __forceinline__ __half2 u2h(unsigned u) {
    union { unsigned u; __half2 h; } c; c.u = u; return c.h;
}

// Load action A_'s 32x32 fp16 transition column sl: 4 x ds_read_b128,
// address-indexed (NO branches). TH[k] = half2(row 2k, row 2k+1).
#define LOADTH(TH, A_) {                                                     \
    const uint4* p_ = sTH + ((A_) << 7) + sl;                                \
    const uint4 q0_ = p_[0], q1_ = p_[32], q2_ = p_[64], q3_ = p_[96];       \
    TH[0]=q0_.x;  TH[1]=q0_.y;  TH[2]=q0_.z;  TH[3]=q0_.w;                   \
    TH[4]=q1_.x;  TH[5]=q1_.y;  TH[6]=q1_.z;  TH[7]=q1_.w;                   \
    TH[8]=q2_.x;  TH[9]=q2_.y;  TH[10]=q2_.z; TH[11]=q2_.w;                  \
    TH[12]=q3_.x; TH[13]=q3_.y; TH[14]=q3_.z; TH[15]=q3_.w; }

// Emission factors for the step encoded in the low 16 bits of PKW (from LDS)
#define LOADE(EO, ERA, PKW) {                                                \
    const unsigned pk_ = (PKW);                                              \
    EO  = sE[(int)(pk_ & 63u) * 32 + sl];                                    \
    ERA = sE[eBase + (int)((pk_ >> 6) & 7u) * eMulR                          \
                   + (int)((pk_ >> 9) & 7u) * eMulA + sl]; }

// Load a full step-pair (2 steps) from the packed word PKW into buffers
#define LOADPAIR(EO0, ERA0, TH0, EO1, ERA1, TH1, PKW) {                      \
    const unsigned pw_ = (PKW);                                              \
    LOADE(EO0, ERA0, pw_ & 0xffffu);                                         \
    LOADE(EO1, ERA1, pw_ >> 16);                                             \
    LOADTH(TH0, (int)((pw_ >> 9) & 7u));                                     \
    LOADTH(TH1, (int)((pw_ >> 25) & 7u)); }

// One HMM step: w = u .* e ; u' = T_a^T w  (32 readlane broadcasts + 32
// mixed-precision fmas against the staged TH regs; 4 accumulator chains)
#define STEP(EO, ERA, TH) {                                                  \
    const float wv = u * (EO) * (ERA);                                       \
    const float w0 =RLF(wv,0),  w1 =RLF(wv,1),  w2 =RLF(wv,2),  w3 =RLF(wv,3),  \
                w4 =RLF(wv,4),  w5 =RLF(wv,5),  w6 =RLF(wv,6),  w7 =RLF(wv,7),  \
                w8 =RLF(wv,8),  w9 =RLF(wv,9),  w10=RLF(wv,10), w11=RLF(wv,11), \
                w12=RLF(wv,12), w13=RLF(wv,13), w14=RLF(wv,14), w15=RLF(wv,15), \
                w16=RLF(wv,16), w17=RLF(wv,17), w18=RLF(wv,18), w19=RLF(wv,19), \
                w20=RLF(wv,20), w21=RLF(wv,21), w22=RLF(wv,22), w23=RLF(wv,23), \
                w24=RLF(wv,24), w25=RLF(wv,25), w26=RLF(wv,26), w27=RLF(wv,27), \
                w28=RLF(wv,28), w29=RLF(wv,29), w30=RLF(wv,30), w31=RLF(wv,31); \
    float c0 = 0.f, c1 = 0.f, c2 = 0.f, c3 = 0.f;                            \
    c0=fmaf(w0, __low2float(u2h(TH[0])), c0); c1=fmaf(w1, __high2float(u2h(TH[0])), c1); \
    c2=fmaf(w2, __low2float(u2h(TH[1])), c2); c3=fmaf(w3, __high2float(u2h(TH[1])), c3); \
    c0=fmaf(w4, __low2float(u2h(TH[2])), c0); c1=fmaf(w5, __high2float(u2h(TH[2])), c1); \
    c2=fmaf(w6, __low2float(u2h(TH[3])), c2); c3=fmaf(w7, __high2float(u2h(TH[3])), c3); \
    c0=fmaf(w8, __low2float(u2h(TH[4])), c0); c1=fmaf(w9, __high2float(u2h(TH[4])), c1); \
    c2=fmaf(w10,__low2float(u2h(TH[5])), c2); c3=fmaf(w11,__high2float(u2h(TH[5])), c3); \
    c0=fmaf(w12,__low2float(u2h(TH[6])), c0); c1=fmaf(w13,__high2float(u2h(TH[6])), c1); \
    c2=fmaf(w14,__low2float(u2h(TH[7])), c2); c3=fmaf(w15,__high2float(u2h(TH[7])), c3); \
    c0=fmaf(w16,__low2float(u2h(TH[8])), c0); c1=fmaf(w17,__high2float(u2h(TH[8])), c1); \
    c2=fmaf(w18,__low2float(u2h(TH[9])), c2); c3=fmaf(w19,__high2float(u2h(TH[9])), c3); \
    c0=fmaf(w20,__low2float(u2h(TH[10])),c0); c1=fmaf(w21,__high2float(u2h(TH[10])),c1); \
    c2=fmaf(w22,__low2float(u2h(TH[11])),c2); c3=fmaf(w23,__high2float(u2h(TH[11])),c3); \
    c0=fmaf(w24,__low2float(u2h(TH[12])),c0); c1=fmaf(w25,__high2float(u2h(TH[12])),c1); \
    c2=fmaf(w26,__low2float(u2h(TH[13])),c2); c3=fmaf(w27,__high2float(u2h(TH[13])),c3); \
    c0=fmaf(w28,__low2float(u2h(TH[14])),c0); c1=fmaf(w29,__high2float(u2h(TH[14])),c1); \
    c2=fmaf(w30,__low2float(u2h(TH[15])),c2); c3=fmaf(w31,__high2float(u2h(TH[15])),c3); \
    u = (c0 + c1) + (c2 + c3); }

// exact power-of-two rescale (SALU exponent math; applied once per pair)
#define RESCALE() {                                                          \
    const int ub = RLI(__float_as_int(u), 0);                                \
    const int kb = (ub >> 23) & 255;                                         \
    u *= __int_as_float((254 - kb) << 23);                                   \
    ksum += kb - 127; }

// 4 waves per block, ONE episode per wave, shared LDS tables. Pair-ahead
// double-buffered pipeline: pair i+2's loads issue a full pair (~2 STEPs)
// before use; X/Y buffer roles alternate statically in a 2-unrolled loop.
__global__ __launch_bounds__(256) void tam_main(
    const float* __restrict__ regime,
    const int*   __restrict__ obs,
    const int*   __restrict__ rewards,
    const int*   __restrict__ dones_i,   // float32 0/1 read as int bits
    const int*   __restrict__ actions,
    const float* __restrict__ ws,
    float* __restrict__ out)
{
    __shared__ uint4 sTH[1024];          // 16 KB packed fp16 transitions
    __shared__ float sE[L_N];            // 17.1 KB emission block
    const int tid  = threadIdx.x;
    const int lane = tid & 63;
    const int wid  = tid >> 6;
    const int sl   = lane & 31;
    const int b    = blockIdx.x * 4 + wid;

    // stage T (16 KB) and emissions (17.1 KB) into LDS — 256 threads
    {
        const uint4* gt = reinterpret_cast<const uint4*>(ws);
        #pragma unroll
        for (int i = 0; i < 4; ++i) sTH[tid + i * 256] = gt[tid + i * 256];
        const float4* ge = reinterpret_cast<const float4*>(ws + OT_OFF);
        float4* s4 = reinterpret_cast<float4*>(sE);
        #pragma unroll 1
        for (int i = tid; i < L_N / 4; i += 256) s4[i] = ge[i];
    }
    __syncthreads();

    // per-lane packed step-pair indices: lane i holds steps 2i (low16), 2i+1 (high16)
    const int t0 = 2 * lane, t1 = 2 * lane + 1;
    const int o0 = obs[t0 * B_N + b],      o1 = obs[t1 * B_N + b];
    const int r0 = rewards[t0 * B_N + b],  r1 = rewards[t1 * B_N + b];
    const int a0 = actions[t0 * B_N + b],  a1 = actions[t1 * B_N + b];
    const int d0 = dones_i[t0 * B_N + b],  d1 = dones_i[t1 * B_N + b];
    const int vpk = (o0 | (r0 << 6) | (a0 << 9)) |
                    ((o1 | (r1 << 6) | (a1 << 9)) << 16);

    // first-done step t* via ballot (per-wave; no done checks in the hot loop)
    const unsigned long long mE = __ballot(d0 != 0);
    const unsigned long long mO = __ballot(d1 != 0);
    const int tE = mE ? 2 * __builtin_ctzll(mE)     : (1 << 30);
    const int tO = mO ? 2 * __builtin_ctzll(mO) + 1 : (1 << 30);
    const int tstar  = tE < tO ? tE : tO;
    const int nsteps = tstar < 128 ? tstar : 128;

    // regime==1 -> action term excluded every step: use RT table (a ignored)
    const bool skipA = (regime[b] == 1.0f);
    const int eBase = skipA ? L_RT : L_RA;
    const int eMulR = skipA ? 32 : 256;
    const int eMulA = skipA ? 0 : 32;

    float u = sE[L_PI + sl];
    int ksum = 0;

    // X/Y pair buffers (all register indices compile-time constant)
    unsigned thX0[16], thX1[16], thY0[16], thY1[16];
    float eoX0, eraX0, eoX1, eraX1, eoY0, eraY0, eoY1, eraY1;

    // prologue: X <- pair 0, Y <- pair 1 (speculative beyond nsteps is safe:
    // readlane lane index wraps mod 64, fields always address valid LDS)
    LOADPAIR(eoX0, eraX0, thX0, eoX1, eraX1, thX1, (unsigned)RLI(vpk, 0));
    LOADPAIR(eoY0, eraY0, thY0, eoY1, eraY1, thY1, (unsigned)RLI(vpk, 1));
    unsigned pkX = (unsigned)RLI(vpk, 2);   // pair index for next X refill
    unsigned pkY = (unsigned)RLI(vpk, 3);

    const int npairs = nsteps >> 1;
    #pragma unroll 1
    for (int i = 0; i + 1 < npairs; i += 2) {
        // pair i from X, then refill X with pair i+2 (consumed next iter:
        // ~2 STEPs + rescales of cover before use)
        STEP(eoX0, eraX0, thX0);
        STEP(eoX1, eraX1, thX1);
        RESCALE();
        LOADPAIR(eoX0, eraX0, thX0, eoX1, eraX1, thX1, pkX);
        pkX = (unsigned)RLI(vpk, i + 4);
        // pair i+1 from Y, refill Y with pair i+3
        STEP(eoY0, eraY0, thY0);
        STEP(eoY1, eraY1, thY1);
        RESCALE();
        LOADPAIR(eoY0, eraY0, thY0, eoY1, eraY1, thY1, pkY);
        pkY = (unsigned)RLI(vpk, i + 5);
    }

    // leftover pair (npairs odd): even-indexed pairs live in X
    if (npairs & 1) {
        STEP(eoX0, eraX0, thX0);
        STEP(eoX1, eraX1, thX1);
        RESCALE();
    }
    // leftover odd step = low half of pair `npairs`: X if npairs even, else Y
    if (nsteps & 1) {
        if (npairs & 1) { STEP(eoY0, eraY0, thY0); }
        else            { STEP(eoX0, eraX0, thX0); }
    }

    // terminal contribution at e = min(t*, 128): OT*RT only (no action term)
    {
        const int e  = nsteps;
        const int oe = obs[e * B_N + b];
        const int re = rewards[e * B_N + b];
        const float eo = sE[L_OT + oe * 32 + sl];
        const float rt = sE[L_RT + re * 32 + sl];
        float t = u * eo * rt;
        t += __shfl_xor(t, 1, 32);
        t += __shfl_xor(t, 2, 32);
        t += __shfl_xor(t, 4, 32);
        t += __shfl_xor(t, 8, 32);
        t += __shfl_xor(t, 16, 32);
        const float result = (float)ksum * 0.69314718055994531f + __logf(t);
        if (lane == 0) out[b] = result;
    }
}

extern "C" void kernel_launch(void* const* d_in, const int* in_sizes, int n_in,
                              void* d_out, int out_size, void* d_ws, size_t ws_size,
                              hipStream_t stream) {
    (void)in_sizes; (void)n_in; (void)out_size; (void)ws_size;
    const float* regime      = (const float*)d_in[0];
    const int*   obs         = (const int*)d_in[1];
    const int*   rewards     = (const int*)d_in[2];
    const int*   dones_i     = (const int*)d_in[3];
    const int*   actions     = (const int*)d_in[4];
    const float* params_s    = (const float*)d_in[5];
    const float* params_s_sa = (const float*)d_in[6];
    const float* params_o_s  = (const float*)d_in[7];
    const float* params_r_s  = (const float*)d_in[8];
    const float* params_a_s  = (const float*)d_in[9];
    float* ws  = (float*)d_ws;
    float* out = (float*)d_out;

    tam_prep<<<2, 256, 0, stream>>>(params_s, params_s_sa, params_o_s,
                                    params_r_s, params_a_s, ws);
    tam_main<<<256, 256, 0, stream>>>(regime, obs, rewards, dones_i, actions, ws, out);
}